// Round 17
// baseline (153.749 us; speedup 1.0000x reference)
//
#include <hip/hip_runtime.h>

#define DIM 128
#define D4 32    // DIM/4
#define D2 64    // DIM/2
#define EPB1 8192   // edges per pass-1 block (16 iters x 512 threads)

typedef short short8 __attribute__((ext_vector_type(8)));   // 8 bf16 in 4 VGPRs
typedef float f32x4 __attribute__((ext_vector_type(4)));

// ---------- bf16 helpers (RNE) ----------
__device__ __forceinline__ unsigned pack_bf16(float a, float b) {
    unsigned ua = __float_as_uint(a);
    unsigned ub = __float_as_uint(b);
    ua = (ua + 0x7FFFu + ((ua >> 16) & 1u)) >> 16;        // RNE
    ub = (ub + 0x7FFFu + ((ub >> 16) & 1u)) & 0xFFFF0000u;
    return ua | ub;   // lo = a, hi = b
}
__device__ __forceinline__ unsigned short bf16_of(float a) {
    unsigned ua = __float_as_uint(a);
    return (unsigned short)((ua + 0x7FFFu + ((ua >> 16) & 1u)) >> 16);
}
__device__ __forceinline__ float blo(unsigned u) { return __uint_as_float(u << 16); }
__device__ __forceinline__ float bhi(unsigned u) { return __uint_as_float(u & 0xFFFF0000u); }

// accumulate 8 bf16 features from one uint4 (function, not macro: a macro param
// named `w` would token-replace the `.w` member access)
__device__ __forceinline__ void acc8(const uint4& v,
                                     float& f0, float& f1, float& f2, float& f3,
                                     float& f4, float& f5, float& f6, float& f7) {
    f0 += blo(v.x); f1 += bhi(v.x);
    f2 += blo(v.y); f3 += bhi(v.y);
    f4 += blo(v.z); f5 += bhi(v.z);
    f6 += blo(v.w); f7 += bhi(v.w);
}

// ================= tier-3: bucketed counting sort (no global-atomic scatter) ==========

// pass 1a: per-block LDS histogram of coarse bucket (dst>>9); extra 8 blocks do W->wt.
__global__ __launch_bounds__(512) void k_hist1(const int* __restrict__ dst, int E,
                                               int* __restrict__ H, int* __restrict__ tot,
                                               int NB1, int NBUCK,
                                               const float* __restrict__ W,
                                               unsigned short* __restrict__ wt) {
    if (blockIdx.x >= (unsigned)NB1) {
        int base = (blockIdx.x - NB1) * 2048 + threadIdx.x * 4;
#pragma unroll
        for (int i = 0; i < 4; ++i) {
            int o = base + i;
            if (o < DIM * DIM) {
                int j = o >> 7, k = o & 127;
                wt[o] = bf16_of(W[k * DIM + j]);
            }
        }
        return;
    }
    __shared__ int h[512];
    const int t = threadIdx.x;
    for (int i = t; i < NBUCK; i += 512) h[i] = 0;
    __syncthreads();
    const int base = blockIdx.x * EPB1;
#pragma unroll
    for (int i = 0; i < EPB1 / 512; ++i) {
        int e = base + i * 512 + t;
        if (e < E) atomicAdd(&h[dst[e] >> 9], 1);
    }
    __syncthreads();
    for (int i = t; i < NBUCK; i += 512) {
        int c = h[i];
        H[i * NB1 + blockIdx.x] = c;
        if (c) atomicAdd(&tot[i], c);
    }
}

// pass 1bc fused: block `bin` recomputes binbase locally from tot, scans its H row.
__global__ __launch_bounds__(512) void k_scanB(int* __restrict__ H,
                                               const int* __restrict__ tot,
                                               int* __restrict__ binbase,
                                               int NB1, int NBUCK, int E) {
    __shared__ int sh[512];
    const int bin = blockIdx.x;
    const int t = threadIdx.x;

    int tv = (t < NBUCK) ? tot[t] : 0;
    sh[t] = tv;
    __syncthreads();
    for (int o = 1; o < 512; o <<= 1) {
        int x = (t >= o) ? sh[t - o] : 0;
        __syncthreads();
        sh[t] += x;
        __syncthreads();
    }
    const int mybase = sh[bin] - ((bin < NBUCK) ? tot[bin] : 0);   // exclusive
    if (t == bin && t < NBUCK) binbase[t] = mybase;
    if (bin == 0 && t == 0) binbase[NBUCK] = E;
    __syncthreads();

    int v = (t < NB1) ? H[bin * NB1 + t] : 0;
    sh[t] = v;
    __syncthreads();
    for (int o = 1; o < 512; o <<= 1) {
        int x = (t >= o) ? sh[t - o] : 0;
        __syncthreads();
        sh[t] += x;
        __syncthreads();
    }
    if (t < NB1) H[bin * NB1 + t] = mybase + sh[t] - v;
}

// pass 1d: scatter packed (src<<9 | dstLo) into per-(bin,blk) runs
__global__ __launch_bounds__(512) void k_scatter1(const int* __restrict__ ei, int E,
                                                  const int* __restrict__ H,
                                                  unsigned* __restrict__ ebuf,
                                                  int NB1, int NBUCK) {
    __shared__ int cnt[512];
    const int t = threadIdx.x;
    const int blk = blockIdx.x;
    for (int i = t; i < NBUCK; i += 512) cnt[i] = 0;
    __syncthreads();
    const int* src = ei;
    const int* dst = ei + E;
    const int base = blk * EPB1;
#pragma unroll
    for (int i = 0; i < EPB1 / 512; ++i) {
        int e = base + i * 512 + t;
        if (e < E) {
            int d = dst[e];
            int s = src[e];
            int b = d >> 9;
            int r = atomicAdd(&cnt[b], 1);
            ebuf[H[b * NB1 + blk] + r] = ((unsigned)s << 9) | (unsigned)(d & 511);
        }
    }
}

// pass 2: one block per bucket: per-node hist (-> dinv, rowstart), local srclist
// scatter, AND xs conversion for this bucket's 512 rows (fused xprep).
__global__ __launch_bounds__(512) void k_bucket2(const unsigned* __restrict__ ebuf,
                                                 const int* __restrict__ binbase,
                                                 int* __restrict__ srclist,
                                                 int* __restrict__ rowstart,
                                                 float* __restrict__ dinv,
                                                 const float* __restrict__ x,
                                                 unsigned* __restrict__ xs,
                                                 int n, int E) {
    __shared__ int h[512];
    __shared__ int off[512];
    __shared__ int cnt[512];
    __shared__ float dinvl[512];
    const int t = threadIdx.x;
    const int b = blockIdx.x;
    const int beg = binbase[b];
    const int end = binbase[b + 1];
    h[t] = 0; cnt[t] = 0;
    __syncthreads();
    for (int j = beg + t; j < end; j += 512) atomicAdd(&h[ebuf[j] & 511], 1);
    __syncthreads();
    int v = h[t];
    off[t] = v;
    __syncthreads();
    for (int o = 1; o < 512; o <<= 1) {
        int x2 = (t >= o) ? off[t - o] : 0;
        __syncthreads();
        off[t] += x2;
        __syncthreads();
    }
    const int excl = off[t] - v;
    const long node = (long)b * 512 + t;
    float dl = rsqrtf((float)(v + 1));
    dinvl[t] = dl;
    if (node < n) {
        rowstart[node] = beg + excl;
        dinv[node] = dl;   // +1 self-loop
    }
    if (b == 0 && t == 0) rowstart[n] = E;
    h[t] = beg + excl;   // start position per lo-bin
    __syncthreads();
    for (int j = beg + t; j < end; j += 512) {
        unsigned p = ebuf[j];
        int lo = p & 511;
        int r = atomicAdd(&cnt[lo], 1);
        srclist[h[lo] + r] = (int)(p >> 9);
    }
    // fused xprep: convert this bucket's rows (dinvl written before the barrier)
    const long rowbase = (long)b * 512;
    for (int i = t; i < 512 * D4; i += 512) {
        int r = i >> 5, c = i & 31;
        long nd = rowbase + r;
        if (nd < n) {
            float dd = dinvl[r];
            float4 v4 = ((const float4*)x)[nd * D4 + c];
            uint2 o;
            o.x = pack_bf16(v4.x * dd, v4.y * dd);
            o.y = pack_bf16(v4.z * dd, v4.w * dd);
            ((uint2*)xs)[nd * D4 + c] = o;
        }
    }
}

// ================= shared tail kernels =================

// xs[i] = bf16(dinv[i] * x[i])  (fallback tiers)
__global__ __launch_bounds__(256) void k_xprep(const float* __restrict__ x,
                                               const float* __restrict__ dinv,
                                               unsigned* __restrict__ xs, int n) {
    long t = (long)blockIdx.x * blockDim.x + threadIdx.x;   // one per float4
    long total = (long)n * D4;
    if (t >= total) return;
    int row = (int)(t >> 5);
    float di = dinv[row];
    float4 v = ((const float4*)x)[t];
    uint2 o;
    o.x = pack_bf16(v.x * di, v.y * di);
    o.y = pack_bf16(v.z * di, v.w * di);
    ((uint2*)xs)[t] = o;
}

// standalone W^T prep (fallback tiers)
__global__ __launch_bounds__(256) void k_wprep(const float* __restrict__ W,
                                               unsigned short* __restrict__ wt) {
    int o = blockIdx.x * blockDim.x + threadIdx.x;
    if (o >= DIM * DIM) return;
    int j = o >> 7, k = o & 127;
    wt[o] = bf16_of(W[k * DIM + j]);
}

// ============ FUSED gather + MFMA transform (tier-3 hot path) ============
// Block = 8 waves (512 thr) = one 16-row tile. R17: waves claim local rows
// DYNAMICALLY via an LDS ticket counter (greedy 16-jobs-on-8-workers) to kill
// barrier convoying from degree variance (static 2-per-wave makespan ~40 edge
// units vs dynamic ~34). All __shfl wave-uniform (ticket via lane0+shfl).
// Phase 2: wave wv computes 16 rows x 16 cols (colbase = wv*16).
// Swizzle: byte_col ^= (row&7)<<4 — same involution on write & read.
__global__ __launch_bounds__(512) void k_gather_mfma(
        const int* __restrict__ rowstart, const int* __restrict__ srclist,
        const uint4* __restrict__ xs4, const float* __restrict__ dinv,
        const unsigned short* __restrict__ WT, const float* __restrict__ bias,
        const float* __restrict__ du, float* __restrict__ out,
        int n) {
    __shared__ unsigned char Atile[16 * 256];   // 16 rows x 128 bf16 (4 KB)
    __shared__ int ticket;

    const int wv   = threadIdx.x >> 6;
    const int lane = threadIdx.x & 63;
    const int g = lane >> 4;     // edge slot / k-chunk group
    const int q = lane & 15;     // 16B slot within row
    const long row0 = (long)blockIdx.x * 16;

    if (threadIdx.x == 0) ticket = 0;
    __syncthreads();

    // ---- phase 1: dynamic per-wave node claim ----
    for (;;) {
        int i0 = 0;
        if (lane == 0) i0 = atomicAdd(&ticket, 1);
        const int lrow = __shfl(i0, 0);        // wave-uniform
        if (lrow >= 16) break;
        const long node = row0 + lrow;         // wave-uniform
        unsigned char* dstb = Atile + lrow * 256 + ((q * 16) ^ ((lrow & 7) << 4));
        if (node < n) {
            const float di = dinv[node];
            float f0 = 0.f, f1 = 0.f, f2 = 0.f, f3 = 0.f,
                  f4 = 0.f, f5 = 0.f, f6 = 0.f, f7 = 0.f;
            if (g == 0) {                      // self-loop
                uint4 v = xs4[node * 16 + q];
                acc8(v, f0, f1, f2, f3, f4, f5, f6, f7);
            }
            const int beg = rowstart[node];
            const int end = rowstart[node + 1];
            for (int base = beg; base < end; base += 64) {
                const int m = (end - base < 64) ? (end - base) : 64;
                int sidx = (base + lane < end) ? srclist[base + lane] : 0;
                int k = 0;
                for (; k + 8 <= m; k += 8) {
                    int sa = __shfl(sidx, k + g);
                    int sb = __shfl(sidx, k + 4 + g);
                    uint4 va = xs4[(long)sa * 16 + q];
                    uint4 vb = xs4[(long)sb * 16 + q];
                    acc8(va, f0, f1, f2, f3, f4, f5, f6, f7);
                    acc8(vb, f0, f1, f2, f3, f4, f5, f6, f7);
                }
                for (; k + 4 <= m; k += 4) {
                    int sa = __shfl(sidx, k + g);
                    uint4 va = xs4[(long)sa * 16 + q];
                    acc8(va, f0, f1, f2, f3, f4, f5, f6, f7);
                }
                const int rem = m - k;          // wave-uniform
                if (rem) {                      // shfl with full exec mask
                    int sa = __shfl(sidx, k + g);
                    if (g < rem) {
                        uint4 va = xs4[(long)sa * 16 + q];
                        acc8(va, f0, f1, f2, f3, f4, f5, f6, f7);
                    }
                }
            }
#pragma unroll
            for (int off = 16; off < 64; off <<= 1) {
                f0 += __shfl_xor(f0, off); f1 += __shfl_xor(f1, off);
                f2 += __shfl_xor(f2, off); f3 += __shfl_xor(f3, off);
                f4 += __shfl_xor(f4, off); f5 += __shfl_xor(f5, off);
                f6 += __shfl_xor(f6, off); f7 += __shfl_xor(f7, off);
            }
            if (g == 0) {
                uint4 o;
                o.x = pack_bf16(f0 * di, f1 * di);
                o.y = pack_bf16(f2 * di, f3 * di);
                o.z = pack_bf16(f4 * di, f5 * di);
                o.w = pack_bf16(f6 * di, f7 * di);
                *(uint4*)dstb = o;
            }
        } else if (g == 0) {
            uint4 z; z.x = z.y = z.z = z.w = 0u;
            *(uint4*)dstb = z;
        }
    }
    __syncthreads();

    // ---- phase 2: MFMA transform; wave wv covers 16 rows x 16 cols ----
    const int lr = lane & 15;
    const int lk8 = g * 8;
    const long grow = row0 + lr;

    short8 afr[4];
#pragma unroll
    for (int ks = 0; ks < 4; ++ks)
        afr[ks] = *(const short8*)(Atile + lr * 256 +
                                   (((ks * 64) + g * 16) ^ ((lr & 7) << 4)));

    const float inv_keep = 1.0f / 0.9f;
    const int colbase = wv * 16;
    f32x4 acc = {0.f, 0.f, 0.f, 0.f};
#pragma unroll
    for (int ks = 0; ks < 4; ++ks) {
        short8 wfr = *reinterpret_cast<const short8*>(
            WT + (long)(colbase + lr) * DIM + ks * 32 + lk8);
        acc = __builtin_amdgcn_mfma_f32_16x16x32_bf16(wfr, afr[ks], acc, 0, 0, 0);
    }
    if (grow < n) {
        const int gcol = colbase + g * 4;
        float4 bb = *reinterpret_cast<const float4*>(bias + gcol);
        float4 u  = *reinterpret_cast<const float4*>(du + grow * DIM + gcol);
        float4 v;
        v.x = acc[0] + bb.x; v.y = acc[1] + bb.y;
        v.z = acc[2] + bb.z; v.w = acc[3] + bb.w;
        v.x = (u.x >= 0.1f) ? fmaxf(v.x, 0.f) * inv_keep : 0.f;
        v.y = (u.y >= 0.1f) ? fmaxf(v.y, 0.f) * inv_keep : 0.f;
        v.z = (u.z >= 0.1f) ? fmaxf(v.z, 0.f) * inv_keep : 0.f;
        v.w = (u.w >= 0.1f) ? fmaxf(v.w, 0.f) * inv_keep : 0.f;
        *reinterpret_cast<float4*>(out + grow * DIM + gcol) = v;
    }
}

// ================= fallback tiers (atomic CSR build, split kernels) =================

__global__ void k_hist(const int* __restrict__ dst, int E, int* __restrict__ hist) {
    int e = blockIdx.x * blockDim.x + threadIdx.x;
    if (e < E) atomicAdd(&hist[dst[e]], 1);
}
__global__ void k_dinv(const int* __restrict__ hist, float* __restrict__ dinv, int n) {
    int i = blockIdx.x * blockDim.x + threadIdx.x;
    if (i < n) dinv[i] = rsqrtf((float)(hist[i] + 1));
}
__global__ __launch_bounds__(256) void k_scan1(const int* __restrict__ hist,
                                               int* __restrict__ rowstart,
                                               int* __restrict__ bsum, int n) {
    __shared__ int sh[256];
    const int t = threadIdx.x;
    const int base = blockIdx.x * 1024 + t * 4;
    int v0 = (base + 0 < n) ? hist[base + 0] : 0;
    int v1 = (base + 1 < n) ? hist[base + 1] : 0;
    int v2 = (base + 2 < n) ? hist[base + 2] : 0;
    int v3 = (base + 3 < n) ? hist[base + 3] : 0;
    int s = v0 + v1 + v2 + v3;
    sh[t] = s;
    __syncthreads();
    for (int off = 1; off < 256; off <<= 1) {
        int xv = (t >= off) ? sh[t - off] : 0;
        __syncthreads();
        sh[t] += xv;
        __syncthreads();
    }
    if (t == 255) bsum[blockIdx.x] = sh[255];
    int run = sh[t] - s;
    if (base + 0 < n) rowstart[base + 0] = run; run += v0;
    if (base + 1 < n) rowstart[base + 1] = run; run += v1;
    if (base + 2 < n) rowstart[base + 2] = run; run += v2;
    if (base + 3 < n) rowstart[base + 3] = run;
}
__global__ __launch_bounds__(256) void k_scan2(int* __restrict__ bsum, int B) {
    __shared__ int sh[256];
    const int t = threadIdx.x;
    int v = (t < B) ? bsum[t] : 0;
    sh[t] = v;
    __syncthreads();
    for (int off = 1; off < 256; off <<= 1) {
        int xv = (t >= off) ? sh[t - off] : 0;
        __syncthreads();
        sh[t] += xv;
        __syncthreads();
    }
    if (t < B) bsum[t] = sh[t] - v;
}
__global__ void k_scan3(int* __restrict__ rowstart, const int* __restrict__ bsum,
                        int n, int E) {
    int i = blockIdx.x * blockDim.x + threadIdx.x;
    if (i < n) rowstart[i] += bsum[i >> 10];
    else if (i == n) rowstart[n] = E;
}
__global__ void k_fill(const int* __restrict__ ei, int E,
                       const int* __restrict__ rowstart, int* __restrict__ cursor,
                       int* __restrict__ srclist) {
    int e = blockIdx.x * blockDim.x + threadIdx.x;
    if (e >= E) return;
    int d = ei[E + e];
    int pos = atomicAdd(&cursor[d], 1);
    srclist[rowstart[d] + pos] = ei[e];
}
__global__ __launch_bounds__(256) void k_gather_bf(const int* __restrict__ rowstart,
                                                   const int* __restrict__ srclist,
                                                   const unsigned* __restrict__ xs,
                                                   const float* __restrict__ dinv,
                                                   float* __restrict__ out, int n) {
    const int node = blockIdx.x * 4 + (threadIdx.x >> 6);
    const int lane = threadIdx.x & 63;
    if (node >= n) return;
    const float di = dinv[node];
    unsigned sv = xs[(long)node * D2 + lane];
    float2 acc;
    acc.x = __uint_as_float(sv << 16);
    acc.y = __uint_as_float(sv & 0xFFFF0000u);
    const int beg = rowstart[node];
    const int end = rowstart[node + 1];
    int j = beg;
    for (; j + 3 < end; j += 4) {
        int s0 = srclist[j]; int s1 = srclist[j + 1];
        int s2 = srclist[j + 2]; int s3 = srclist[j + 3];
        unsigned v0 = xs[(long)s0 * D2 + lane];
        unsigned v1 = xs[(long)s1 * D2 + lane];
        unsigned v2 = xs[(long)s2 * D2 + lane];
        unsigned v3 = xs[(long)s3 * D2 + lane];
        acc.x += __uint_as_float(v0 << 16) + __uint_as_float(v1 << 16)
               + __uint_as_float(v2 << 16) + __uint_as_float(v3 << 16);
        acc.y += __uint_as_float(v0 & 0xFFFF0000u) + __uint_as_float(v1 & 0xFFFF0000u)
               + __uint_as_float(v2 & 0xFFFF0000u) + __uint_as_float(v3 & 0xFFFF0000u);
    }
    for (; j < end; ++j) {
        unsigned v0 = xs[(long)srclist[j] * D2 + lane];
        acc.x += __uint_as_float(v0 << 16);
        acc.y += __uint_as_float(v0 & 0xFFFF0000u);
    }
    acc.x *= di; acc.y *= di;
    ((float2*)out)[(long)node * D2 + lane] = acc;
}

// fallback per-node bf16 gather to global agg (tier-2)
__global__ __launch_bounds__(256) void k_gather_bb(const int* __restrict__ rowstart,
                                                   const int* __restrict__ srclist,
                                                   const uint4* __restrict__ xs4,
                                                   const float* __restrict__ dinv,
                                                   uint4* __restrict__ agg4, int n) {
    const int node = blockIdx.x * 4 + (threadIdx.x >> 6);
    const int lane = threadIdx.x & 63;
    if (node >= n) return;
    const int g = lane >> 4;
    const int q = lane & 15;
    const float di = dinv[node];

    float f0 = 0.f, f1 = 0.f, f2 = 0.f, f3 = 0.f,
          f4 = 0.f, f5 = 0.f, f6 = 0.f, f7 = 0.f;
    if (g == 0) {
        uint4 v = xs4[(long)node * 16 + q];
        acc8(v, f0, f1, f2, f3, f4, f5, f6, f7);
    }
    const int beg = rowstart[node];
    const int end = rowstart[node + 1];
    for (int base = beg; base < end; base += 64) {
        const int m = (end - base < 64) ? (end - base) : 64;
        int sidx = (base + lane < end) ? srclist[base + lane] : 0;
        int k = 0;
        for (; k + 8 <= m; k += 8) {
            int sa = __shfl(sidx, k + g);
            int sb = __shfl(sidx, k + 4 + g);
            uint4 va = xs4[(long)sa * 16 + q];
            uint4 vb = xs4[(long)sb * 16 + q];
            acc8(va, f0, f1, f2, f3, f4, f5, f6, f7);
            acc8(vb, f0, f1, f2, f3, f4, f5, f6, f7);
        }
        for (; k + 4 <= m; k += 4) {
            int sa = __shfl(sidx, k + g);
            uint4 va = xs4[(long)sa * 16 + q];
            acc8(va, f0, f1, f2, f3, f4, f5, f6, f7);
        }
        const int rem = m - k;
        if (rem) {
            int sa = __shfl(sidx, k + g);
            if (g < rem) {
                uint4 va = xs4[(long)sa * 16 + q];
                acc8(va, f0, f1, f2, f3, f4, f5, f6, f7);
            }
        }
    }
#pragma unroll
    for (int off = 16; off < 64; off <<= 1) {
        f0 += __shfl_xor(f0, off); f1 += __shfl_xor(f1, off);
        f2 += __shfl_xor(f2, off); f3 += __shfl_xor(f3, off);
        f4 += __shfl_xor(f4, off); f5 += __shfl_xor(f5, off);
        f6 += __shfl_xor(f6, off); f7 += __shfl_xor(f7, off);
    }
    if (g == 0) {
        uint4 o;
        o.x = pack_bf16(f0 * di, f1 * di);
        o.y = pack_bf16(f2 * di, f3 * di);
        o.z = pack_bf16(f4 * di, f5 * di);
        o.w = pack_bf16(f6 * di, f7 * di);
        agg4[(long)node * 16 + q] = o;
    }
}

// fallback standalone MFMA transform (tier-2)
__global__ __launch_bounds__(256) void k_mfma_transform(
        const unsigned short* __restrict__ A, const unsigned short* __restrict__ WT,
        const float* __restrict__ bias, const float* __restrict__ du,
        float* __restrict__ out, int n, int ntiles) {
    const int wave  = threadIdx.x >> 6;
    const int lane  = threadIdx.x & 63;
    const int rhalf = wave >> 1;
    const int cg    = wave & 1;
    const int lr    = lane & 15;
    const int g     = lane >> 4;
    const int lk8   = g * 8;

    const int t = blockIdx.x;
    if (t >= ntiles) return;
    const long row0 = (long)t * 32 + rhalf * 16;
    const long grow = row0 + lr;

    long ar = grow; if (ar >= n) ar = n - 1;
    short8 afr[4];
#pragma unroll
    for (int ks = 0; ks < 4; ++ks)
        afr[ks] = *reinterpret_cast<const short8*>(A + ar * DIM + ks * 32 + lk8);

    const float inv_keep = 1.0f / 0.9f;
#pragma unroll
    for (int ct = 0; ct < 4; ++ct) {
        const int colbase = cg * 64 + ct * 16;
        f32x4 acc = {0.f, 0.f, 0.f, 0.f};
#pragma unroll
        for (int ks = 0; ks < 4; ++ks) {
            short8 wfr = *reinterpret_cast<const short8*>(
                WT + (long)(colbase + lr) * DIM + ks * 32 + lk8);
            acc = __builtin_amdgcn_mfma_f32_16x16x32_bf16(wfr, afr[ks], acc, 0, 0, 0);
        }
        if (grow < n) {
            const int gcol = colbase + g * 4;
            float4 bb = *reinterpret_cast<const float4*>(bias + gcol);
            float4 u  = *reinterpret_cast<const float4*>(du + grow * DIM + gcol);
            float4 v;
            v.x = acc[0] + bb.x; v.y = acc[1] + bb.y;
            v.z = acc[2] + bb.z; v.w = acc[3] + bb.w;
            v.x = (u.x >= 0.1f) ? fmaxf(v.x, 0.f) * inv_keep : 0.f;
            v.y = (u.y >= 0.1f) ? fmaxf(v.y, 0.f) * inv_keep : 0.f;
            v.z = (u.z >= 0.1f) ? fmaxf(v.z, 0.f) * inv_keep : 0.f;
            v.w = (u.w >= 0.1f) ? fmaxf(v.w, 0.f) * inv_keep : 0.f;
            *reinterpret_cast<float4*>(out + grow * DIM + gcol) = v;
        }
    }
}

extern "C" void kernel_launch(void* const* d_in, const int* in_sizes, int n_in,
                              void* d_out, int out_size, void* d_ws, size_t ws_size,
                              hipStream_t stream) {
    const float* x  = (const float*)d_in[0];
    const int*   ei = (const int*)d_in[1];    // [2,E] int32: row0=src, row1=dst
    const float* W  = (const float*)d_in[2];
    const float* b  = (const float*)d_in[3];
    const float* du = (const float*)d_in[4];
    float* out = (float*)d_out;

    const int n = in_sizes[0] / DIM;
    const int E = in_sizes[1] / 2;

    auto al = [](size_t v) { return (v + 255) & ~(size_t)255; };
    char* ws = (char*)d_ws;

    const int NBUCK = (n + 511) >> 9;
    const int NB1   = (E + EPB1 - 1) / EPB1;

    // ---- tier-3 layout ----
    size_t o_dinv = 0;
    size_t o_rs   = o_dinv + al((size_t)n * 4);
    size_t o_src  = o_rs   + al(((size_t)n + 1) * 4);
    size_t o_xs   = o_src  + al((size_t)E * 4);
    size_t o_agg  = o_xs   + al((size_t)n * DIM * 2);
    size_t o_wt   = o_agg  + al((size_t)n * DIM * 2);
    size_t o_H    = o_wt   + al((size_t)DIM * DIM * 2);
    size_t o_tot  = o_H    + al((size_t)NBUCK * NB1 * 4);
    size_t o_bb   = o_tot  + al((size_t)NBUCK * 4);
    size_t o_ebuf = o_bb   + al(((size_t)NBUCK + 1) * 4);
    size_t need3  = o_ebuf + (size_t)E * 4;

    float* dinv     = (float*)(ws + o_dinv);
    int*   rowstart = (int*)(ws + o_rs);
    int*   srclist  = (int*)(ws + o_src);
    unsigned* xs    = (unsigned*)(ws + o_xs);
    unsigned* agg   = (unsigned*)(ws + o_agg);
    unsigned short* wt = (unsigned short*)(ws + o_wt);
    int*   H        = (int*)(ws + o_H);
    int*   tot      = (int*)(ws + o_tot);
    int*   binbase  = (int*)(ws + o_bb);
    unsigned* ebuf  = (unsigned*)(ws + o_ebuf);

    const int bs = 256;

    if (ws_size >= need3 && NBUCK <= 512 && NB1 <= 512) {
        (void)hipMemsetAsync(tot, 0, (size_t)NBUCK * 4, stream);
        k_hist1<<<NB1 + 8, 512, 0, stream>>>(ei + E, E, H, tot, NB1, NBUCK, W, wt);
        k_scanB<<<NBUCK, 512, 0, stream>>>(H, tot, binbase, NB1, NBUCK, E);
        k_scatter1<<<NB1, 512, 0, stream>>>(ei, E, H, ebuf, NB1, NBUCK);
        k_bucket2<<<NBUCK, 512, 0, stream>>>(ebuf, binbase, srclist, rowstart, dinv,
                                             x, xs, n, E);

        int ntiles16 = (n + 15) / 16;
        k_gather_mfma<<<ntiles16, 512, 0, stream>>>(rowstart, srclist,
                                                    (const uint4*)xs, dinv,
                                                    wt, b, du, out, n);
        return;
    }

    // ---- fallback tiers: atomic CSR build ----
    size_t f_dinv = 0;
    size_t f_hist = f_dinv + al((size_t)n * 4);
    size_t f_rs   = f_hist + al((size_t)n * 4);
    size_t f_bsum = f_rs   + al(((size_t)n + 1) * 4);
    size_t f_src  = f_bsum + 1024;
    size_t f_xs   = f_src  + al((size_t)E * 4);
    size_t f_agg  = f_xs   + al((size_t)n * DIM * 2);
    size_t f_wt   = f_agg  + al((size_t)n * DIM * 2);
    size_t need1  = f_agg;
    size_t need2  = f_wt + (size_t)DIM * DIM * 2;

    float* fdinv     = (float*)(ws + f_dinv);
    int*   fhist     = (int*)(ws + f_hist);
    int*   frowstart = (int*)(ws + f_rs);
    int*   fbsum     = (int*)(ws + f_bsum);
    int*   fsrclist  = (int*)(ws + f_src);
    unsigned* fxs    = (unsigned*)(ws + f_xs);
    unsigned* fagg   = (unsigned*)(ws + f_agg);
    unsigned short* fwt = (unsigned short*)(ws + f_wt);

    const int B = (n + 1023) / 1024;
    (void)hipMemsetAsync(fhist, 0, (size_t)n * 4, stream);
    k_hist<<<(E + bs - 1) / bs, bs, 0, stream>>>(ei + E, E, fhist);
    k_dinv<<<(n + bs - 1) / bs, bs, 0, stream>>>(fhist, fdinv, n);
    k_scan1<<<B, 256, 0, stream>>>(fhist, frowstart, fbsum, n);
    k_scan2<<<1, 256, 0, stream>>>(fbsum, B);
    k_scan3<<<(n + 1 + bs - 1) / bs, bs, 0, stream>>>(frowstart, fbsum, n, E);
    (void)hipMemsetAsync(fhist, 0, (size_t)n * 4, stream);
    k_fill<<<(E + bs - 1) / bs, bs, 0, stream>>>(ei, E, frowstart, fhist, fsrclist);

    if (ws_size >= need2) {
        long t_x = (long)n * D4;
        k_xprep<<<(int)((t_x + bs - 1) / bs), bs, 0, stream>>>(x, fdinv, fxs, n);
        k_wprep<<<(DIM * DIM + bs - 1) / bs, bs, 0, stream>>>(W, fwt);
        k_gather_bb<<<(n + 3) / 4, 256, 0, stream>>>(frowstart, fsrclist,
                                                     (const uint4*)fxs, fdinv,
                                                     (uint4*)fagg, n);
        int ntiles = (n + 31) / 32;
        k_mfma_transform<<<ntiles, 256, 0, stream>>>((const unsigned short*)fagg, fwt,
                                                     b, du, out, n, ntiles);
    } else if (ws_size >= need1) {
        long t_x = (long)n * D4;
        k_xprep<<<(int)((t_x + bs - 1) / bs), bs, 0, stream>>>(x, fdinv, fxs, n);
        k_gather_bf<<<(n + 3) / 4, 256, 0, stream>>>(frowstart, fsrclist, fxs, fdinv, out, n);
    }
}

// Round 18
// 151.056 us; speedup vs baseline: 1.0178x; 1.0178x over previous
//
#include <hip/hip_runtime.h>

#define DIM 128
#define D4 32    // DIM/4
#define D2 64    // DIM/2
#define EPB1 8192   // edges per pass-1 block (16 iters x 512 threads)

typedef short short8 __attribute__((ext_vector_type(8)));   // 8 bf16 in 4 VGPRs
typedef float f32x4 __attribute__((ext_vector_type(4)));

// ---------- bf16 helpers (RNE) ----------
__device__ __forceinline__ unsigned pack_bf16(float a, float b) {
    unsigned ua = __float_as_uint(a);
    unsigned ub = __float_as_uint(b);
    ua = (ua + 0x7FFFu + ((ua >> 16) & 1u)) >> 16;        // RNE
    ub = (ub + 0x7FFFu + ((ub >> 16) & 1u)) & 0xFFFF0000u;
    return ua | ub;   // lo = a, hi = b
}
__device__ __forceinline__ unsigned short bf16_of(float a) {
    unsigned ua = __float_as_uint(a);
    return (unsigned short)((ua + 0x7FFFu + ((ua >> 16) & 1u)) >> 16);
}
__device__ __forceinline__ float blo(unsigned u) { return __uint_as_float(u << 16); }
__device__ __forceinline__ float bhi(unsigned u) { return __uint_as_float(u & 0xFFFF0000u); }

// accumulate 8 bf16 features from one uint4 (function, not macro: a macro param
// named `w` would token-replace the `.w` member access)
__device__ __forceinline__ void acc8(const uint4& v,
                                     float& f0, float& f1, float& f2, float& f3,
                                     float& f4, float& f5, float& f6, float& f7) {
    f0 += blo(v.x); f1 += bhi(v.x);
    f2 += blo(v.y); f3 += bhi(v.y);
    f4 += blo(v.z); f5 += bhi(v.z);
    f6 += blo(v.w); f7 += bhi(v.w);
}

// ================= tier-3: bucketed counting sort (no global-atomic scatter) ==========

// pass 1a: per-block LDS histogram of coarse bucket (dst>>9); extra 8 blocks do W->wt.
__global__ __launch_bounds__(512) void k_hist1(const int* __restrict__ dst, int E,
                                               int* __restrict__ H, int* __restrict__ tot,
                                               int NB1, int NBUCK,
                                               const float* __restrict__ W,
                                               unsigned short* __restrict__ wt) {
    if (blockIdx.x >= (unsigned)NB1) {
        int base = (blockIdx.x - NB1) * 2048 + threadIdx.x * 4;
#pragma unroll
        for (int i = 0; i < 4; ++i) {
            int o = base + i;
            if (o < DIM * DIM) {
                int j = o >> 7, k = o & 127;
                wt[o] = bf16_of(W[k * DIM + j]);
            }
        }
        return;
    }
    __shared__ int h[512];
    const int t = threadIdx.x;
    for (int i = t; i < NBUCK; i += 512) h[i] = 0;
    __syncthreads();
    const int base = blockIdx.x * EPB1;
#pragma unroll
    for (int i = 0; i < EPB1 / 512; ++i) {
        int e = base + i * 512 + t;
        if (e < E) atomicAdd(&h[dst[e] >> 9], 1);
    }
    __syncthreads();
    for (int i = t; i < NBUCK; i += 512) {
        int c = h[i];
        H[i * NB1 + blockIdx.x] = c;
        if (c) atomicAdd(&tot[i], c);
    }
}

// pass 1bc fused: block `bin` recomputes binbase locally from tot, scans its H row.
__global__ __launch_bounds__(512) void k_scanB(int* __restrict__ H,
                                               const int* __restrict__ tot,
                                               int* __restrict__ binbase,
                                               int NB1, int NBUCK, int E) {
    __shared__ int sh[512];
    const int bin = blockIdx.x;
    const int t = threadIdx.x;

    int tv = (t < NBUCK) ? tot[t] : 0;
    sh[t] = tv;
    __syncthreads();
    for (int o = 1; o < 512; o <<= 1) {
        int x = (t >= o) ? sh[t - o] : 0;
        __syncthreads();
        sh[t] += x;
        __syncthreads();
    }
    const int mybase = sh[bin] - ((bin < NBUCK) ? tot[bin] : 0);   // exclusive
    if (t == bin && t < NBUCK) binbase[t] = mybase;
    if (bin == 0 && t == 0) binbase[NBUCK] = E;
    __syncthreads();

    int v = (t < NB1) ? H[bin * NB1 + t] : 0;
    sh[t] = v;
    __syncthreads();
    for (int o = 1; o < 512; o <<= 1) {
        int x = (t >= o) ? sh[t - o] : 0;
        __syncthreads();
        sh[t] += x;
        __syncthreads();
    }
    if (t < NB1) H[bin * NB1 + t] = mybase + sh[t] - v;
}

// pass 1d: scatter packed (src<<9 | dstLo) into per-(bin,blk) runs
__global__ __launch_bounds__(512) void k_scatter1(const int* __restrict__ ei, int E,
                                                  const int* __restrict__ H,
                                                  unsigned* __restrict__ ebuf,
                                                  int NB1, int NBUCK) {
    __shared__ int cnt[512];
    const int t = threadIdx.x;
    const int blk = blockIdx.x;
    for (int i = t; i < NBUCK; i += 512) cnt[i] = 0;
    __syncthreads();
    const int* src = ei;
    const int* dst = ei + E;
    const int base = blk * EPB1;
#pragma unroll
    for (int i = 0; i < EPB1 / 512; ++i) {
        int e = base + i * 512 + t;
        if (e < E) {
            int d = dst[e];
            int s = src[e];
            int b = d >> 9;
            int r = atomicAdd(&cnt[b], 1);
            ebuf[H[b * NB1 + blk] + r] = ((unsigned)s << 9) | (unsigned)(d & 511);
        }
    }
}

// pass 2: one block per bucket: per-node hist (-> dinv, rowstart), local srclist
// scatter, AND xs conversion for this bucket's 512 rows (fused xprep).
__global__ __launch_bounds__(512) void k_bucket2(const unsigned* __restrict__ ebuf,
                                                 const int* __restrict__ binbase,
                                                 int* __restrict__ srclist,
                                                 int* __restrict__ rowstart,
                                                 float* __restrict__ dinv,
                                                 const float* __restrict__ x,
                                                 unsigned* __restrict__ xs,
                                                 int n, int E) {
    __shared__ int h[512];
    __shared__ int off[512];
    __shared__ int cnt[512];
    __shared__ float dinvl[512];
    const int t = threadIdx.x;
    const int b = blockIdx.x;
    const int beg = binbase[b];
    const int end = binbase[b + 1];
    h[t] = 0; cnt[t] = 0;
    __syncthreads();
    for (int j = beg + t; j < end; j += 512) atomicAdd(&h[ebuf[j] & 511], 1);
    __syncthreads();
    int v = h[t];
    off[t] = v;
    __syncthreads();
    for (int o = 1; o < 512; o <<= 1) {
        int x2 = (t >= o) ? off[t - o] : 0;
        __syncthreads();
        off[t] += x2;
        __syncthreads();
    }
    const int excl = off[t] - v;
    const long node = (long)b * 512 + t;
    float dl = rsqrtf((float)(v + 1));
    dinvl[t] = dl;
    if (node < n) {
        rowstart[node] = beg + excl;
        dinv[node] = dl;   // +1 self-loop
    }
    if (b == 0 && t == 0) rowstart[n] = E;
    h[t] = beg + excl;   // start position per lo-bin
    __syncthreads();
    for (int j = beg + t; j < end; j += 512) {
        unsigned p = ebuf[j];
        int lo = p & 511;
        int r = atomicAdd(&cnt[lo], 1);
        srclist[h[lo] + r] = (int)(p >> 9);
    }
    // fused xprep: convert this bucket's rows (dinvl written before the barrier)
    const long rowbase = (long)b * 512;
    for (int i = t; i < 512 * D4; i += 512) {
        int r = i >> 5, c = i & 31;
        long nd = rowbase + r;
        if (nd < n) {
            float dd = dinvl[r];
            float4 v4 = ((const float4*)x)[nd * D4 + c];
            uint2 o;
            o.x = pack_bf16(v4.x * dd, v4.y * dd);
            o.y = pack_bf16(v4.z * dd, v4.w * dd);
            ((uint2*)xs)[nd * D4 + c] = o;
        }
    }
}

// ================= shared tail kernels =================

// xs[i] = bf16(dinv[i] * x[i])  (fallback tiers)
__global__ __launch_bounds__(256) void k_xprep(const float* __restrict__ x,
                                               const float* __restrict__ dinv,
                                               unsigned* __restrict__ xs, int n) {
    long t = (long)blockIdx.x * blockDim.x + threadIdx.x;   // one per float4
    long total = (long)n * D4;
    if (t >= total) return;
    int row = (int)(t >> 5);
    float di = dinv[row];
    float4 v = ((const float4*)x)[t];
    uint2 o;
    o.x = pack_bf16(v.x * di, v.y * di);
    o.y = pack_bf16(v.z * di, v.w * di);
    ((uint2*)xs)[t] = o;
}

// standalone W^T prep (fallback tiers)
__global__ __launch_bounds__(256) void k_wprep(const float* __restrict__ W,
                                               unsigned short* __restrict__ wt) {
    int o = blockIdx.x * blockDim.x + threadIdx.x;
    if (o >= DIM * DIM) return;
    int j = o >> 7, k = o & 127;
    wt[o] = bf16_of(W[k * DIM + j]);
}

// ============ FUSED gather + MFMA transform (tier-3 hot path) ============
// Block = 8 waves (512 thr) = one 16-row tile; wave wv gathers nodes
// 16t+2wv, 16t+2wv+1 (50k gather waves), then computes 16 rows x 16 cols
// (colbase = wv*16). R14/R16 configuration — VGPR 24 / occupancy ~79%, the
// measured optimum. R15 (preload/ILP, VGPR 40, occ 61%) and R17 (dynamic
// ticket) both regressed — this latency-bound gather wants max resident
// waves and minimal per-wave overhead.
// Swizzle: byte_col ^= (row&7)<<4 — same involution on write & read.
// All __shfl in wave-uniform control flow.
__global__ __launch_bounds__(512) void k_gather_mfma(
        const int* __restrict__ rowstart, const int* __restrict__ srclist,
        const uint4* __restrict__ xs4, const float* __restrict__ dinv,
        const unsigned short* __restrict__ WT, const float* __restrict__ bias,
        const float* __restrict__ du, float* __restrict__ out,
        int n) {
    __shared__ unsigned char Atile[16 * 256];   // 16 rows x 128 bf16 (4 KB)

    const int wv   = threadIdx.x >> 6;
    const int lane = threadIdx.x & 63;
    const int g = lane >> 4;     // edge slot / k-chunk group
    const int q = lane & 15;     // 16B slot within row
    const long row0 = (long)blockIdx.x * 16;

    // ---- phase 1: gather 2 nodes per wave ----
    for (int nd = 0; nd < 2; ++nd) {
        const int lrow = wv * 2 + nd;          // 0..15 local row
        const long node = row0 + lrow;         // wave-uniform
        unsigned char* dstb = Atile + lrow * 256 + ((q * 16) ^ ((lrow & 7) << 4));
        if (node < n) {
            const float di = dinv[node];
            float f0 = 0.f, f1 = 0.f, f2 = 0.f, f3 = 0.f,
                  f4 = 0.f, f5 = 0.f, f6 = 0.f, f7 = 0.f;
            if (g == 0) {                      // self-loop
                uint4 v = xs4[node * 16 + q];
                acc8(v, f0, f1, f2, f3, f4, f5, f6, f7);
            }
            const int beg = rowstart[node];
            const int end = rowstart[node + 1];
            for (int base = beg; base < end; base += 64) {
                const int m = (end - base < 64) ? (end - base) : 64;
                int sidx = (base + lane < end) ? srclist[base + lane] : 0;
                int k = 0;
                for (; k + 8 <= m; k += 8) {
                    int sa = __shfl(sidx, k + g);
                    int sb = __shfl(sidx, k + 4 + g);
                    uint4 va = xs4[(long)sa * 16 + q];
                    uint4 vb = xs4[(long)sb * 16 + q];
                    acc8(va, f0, f1, f2, f3, f4, f5, f6, f7);
                    acc8(vb, f0, f1, f2, f3, f4, f5, f6, f7);
                }
                for (; k + 4 <= m; k += 4) {
                    int sa = __shfl(sidx, k + g);
                    uint4 va = xs4[(long)sa * 16 + q];
                    acc8(va, f0, f1, f2, f3, f4, f5, f6, f7);
                }
                const int rem = m - k;          // wave-uniform
                if (rem) {                      // shfl with full exec mask
                    int sa = __shfl(sidx, k + g);
                    if (g < rem) {
                        uint4 va = xs4[(long)sa * 16 + q];
                        acc8(va, f0, f1, f2, f3, f4, f5, f6, f7);
                    }
                }
            }
#pragma unroll
            for (int off = 16; off < 64; off <<= 1) {
                f0 += __shfl_xor(f0, off); f1 += __shfl_xor(f1, off);
                f2 += __shfl_xor(f2, off); f3 += __shfl_xor(f3, off);
                f4 += __shfl_xor(f4, off); f5 += __shfl_xor(f5, off);
                f6 += __shfl_xor(f6, off); f7 += __shfl_xor(f7, off);
            }
            if (g == 0) {
                uint4 o;
                o.x = pack_bf16(f0 * di, f1 * di);
                o.y = pack_bf16(f2 * di, f3 * di);
                o.z = pack_bf16(f4 * di, f5 * di);
                o.w = pack_bf16(f6 * di, f7 * di);
                *(uint4*)dstb = o;
            }
        } else if (g == 0) {
            uint4 z; z.x = z.y = z.z = z.w = 0u;
            *(uint4*)dstb = z;
        }
    }
    __syncthreads();

    // ---- phase 2: MFMA transform; wave wv covers 16 rows x 16 cols ----
    const int lr = lane & 15;
    const int lk8 = g * 8;
    const long grow = row0 + lr;

    short8 afr[4];
#pragma unroll
    for (int ks = 0; ks < 4; ++ks)
        afr[ks] = *(const short8*)(Atile + lr * 256 +
                                   (((ks * 64) + g * 16) ^ ((lr & 7) << 4)));

    const float inv_keep = 1.0f / 0.9f;
    const int colbase = wv * 16;
    f32x4 acc = {0.f, 0.f, 0.f, 0.f};
#pragma unroll
    for (int ks = 0; ks < 4; ++ks) {
        short8 wfr = *reinterpret_cast<const short8*>(
            WT + (long)(colbase + lr) * DIM + ks * 32 + lk8);
        acc = __builtin_amdgcn_mfma_f32_16x16x32_bf16(wfr, afr[ks], acc, 0, 0, 0);
    }
    if (grow < n) {
        const int gcol = colbase + g * 4;
        float4 bb = *reinterpret_cast<const float4*>(bias + gcol);
        float4 u  = *reinterpret_cast<const float4*>(du + grow * DIM + gcol);
        float4 v;
        v.x = acc[0] + bb.x; v.y = acc[1] + bb.y;
        v.z = acc[2] + bb.z; v.w = acc[3] + bb.w;
        v.x = (u.x >= 0.1f) ? fmaxf(v.x, 0.f) * inv_keep : 0.f;
        v.y = (u.y >= 0.1f) ? fmaxf(v.y, 0.f) * inv_keep : 0.f;
        v.z = (u.z >= 0.1f) ? fmaxf(v.z, 0.f) * inv_keep : 0.f;
        v.w = (u.w >= 0.1f) ? fmaxf(v.w, 0.f) * inv_keep : 0.f;
        *reinterpret_cast<float4*>(out + grow * DIM + gcol) = v;
    }
}

// ================= fallback tiers (atomic CSR build, split kernels) =================

__global__ void k_hist(const int* __restrict__ dst, int E, int* __restrict__ hist) {
    int e = blockIdx.x * blockDim.x + threadIdx.x;
    if (e < E) atomicAdd(&hist[dst[e]], 1);
}
__global__ void k_dinv(const int* __restrict__ hist, float* __restrict__ dinv, int n) {
    int i = blockIdx.x * blockDim.x + threadIdx.x;
    if (i < n) dinv[i] = rsqrtf((float)(hist[i] + 1));
}
__global__ __launch_bounds__(256) void k_scan1(const int* __restrict__ hist,
                                               int* __restrict__ rowstart,
                                               int* __restrict__ bsum, int n) {
    __shared__ int sh[256];
    const int t = threadIdx.x;
    const int base = blockIdx.x * 1024 + t * 4;
    int v0 = (base + 0 < n) ? hist[base + 0] : 0;
    int v1 = (base + 1 < n) ? hist[base + 1] : 0;
    int v2 = (base + 2 < n) ? hist[base + 2] : 0;
    int v3 = (base + 3 < n) ? hist[base + 3] : 0;
    int s = v0 + v1 + v2 + v3;
    sh[t] = s;
    __syncthreads();
    for (int off = 1; off < 256; off <<= 1) {
        int xv = (t >= off) ? sh[t - off] : 0;
        __syncthreads();
        sh[t] += xv;
        __syncthreads();
    }
    if (t == 255) bsum[blockIdx.x] = sh[255];
    int run = sh[t] - s;
    if (base + 0 < n) rowstart[base + 0] = run; run += v0;
    if (base + 1 < n) rowstart[base + 1] = run; run += v1;
    if (base + 2 < n) rowstart[base + 2] = run; run += v2;
    if (base + 3 < n) rowstart[base + 3] = run;
}
__global__ __launch_bounds__(256) void k_scan2(int* __restrict__ bsum, int B) {
    __shared__ int sh[256];
    const int t = threadIdx.x;
    int v = (t < B) ? bsum[t] : 0;
    sh[t] = v;
    __syncthreads();
    for (int off = 1; off < 256; off <<= 1) {
        int xv = (t >= off) ? sh[t - off] : 0;
        __syncthreads();
        sh[t] += xv;
        __syncthreads();
    }
    if (t < B) bsum[t] = sh[t] - v;
}
__global__ void k_scan3(int* __restrict__ rowstart, const int* __restrict__ bsum,
                        int n, int E) {
    int i = blockIdx.x * blockDim.x + threadIdx.x;
    if (i < n) rowstart[i] += bsum[i >> 10];
    else if (i == n) rowstart[n] = E;
}
__global__ void k_fill(const int* __restrict__ ei, int E,
                       const int* __restrict__ rowstart, int* __restrict__ cursor,
                       int* __restrict__ srclist) {
    int e = blockIdx.x * blockDim.x + threadIdx.x;
    if (e >= E) return;
    int d = ei[E + e];
    int pos = atomicAdd(&cursor[d], 1);
    srclist[rowstart[d] + pos] = ei[e];
}
__global__ __launch_bounds__(256) void k_gather_bf(const int* __restrict__ rowstart,
                                                   const int* __restrict__ srclist,
                                                   const unsigned* __restrict__ xs,
                                                   const float* __restrict__ dinv,
                                                   float* __restrict__ out, int n) {
    const int node = blockIdx.x * 4 + (threadIdx.x >> 6);
    const int lane = threadIdx.x & 63;
    if (node >= n) return;
    const float di = dinv[node];
    unsigned sv = xs[(long)node * D2 + lane];
    float2 acc;
    acc.x = __uint_as_float(sv << 16);
    acc.y = __uint_as_float(sv & 0xFFFF0000u);
    const int beg = rowstart[node];
    const int end = rowstart[node + 1];
    int j = beg;
    for (; j + 3 < end; j += 4) {
        int s0 = srclist[j]; int s1 = srclist[j + 1];
        int s2 = srclist[j + 2]; int s3 = srclist[j + 3];
        unsigned v0 = xs[(long)s0 * D2 + lane];
        unsigned v1 = xs[(long)s1 * D2 + lane];
        unsigned v2 = xs[(long)s2 * D2 + lane];
        unsigned v3 = xs[(long)s3 * D2 + lane];
        acc.x += __uint_as_float(v0 << 16) + __uint_as_float(v1 << 16)
               + __uint_as_float(v2 << 16) + __uint_as_float(v3 << 16);
        acc.y += __uint_as_float(v0 & 0xFFFF0000u) + __uint_as_float(v1 & 0xFFFF0000u)
               + __uint_as_float(v2 & 0xFFFF0000u) + __uint_as_float(v3 & 0xFFFF0000u);
    }
    for (; j < end; ++j) {
        unsigned v0 = xs[(long)srclist[j] * D2 + lane];
        acc.x += __uint_as_float(v0 << 16);
        acc.y += __uint_as_float(v0 & 0xFFFF0000u);
    }
    acc.x *= di; acc.y *= di;
    ((float2*)out)[(long)node * D2 + lane] = acc;
}

// fallback per-node bf16 gather to global agg (tier-2)
__global__ __launch_bounds__(256) void k_gather_bb(const int* __restrict__ rowstart,
                                                   const int* __restrict__ srclist,
                                                   const uint4* __restrict__ xs4,
                                                   const float* __restrict__ dinv,
                                                   uint4* __restrict__ agg4, int n) {
    const int node = blockIdx.x * 4 + (threadIdx.x >> 6);
    const int lane = threadIdx.x & 63;
    if (node >= n) return;
    const int g = lane >> 4;
    const int q = lane & 15;
    const float di = dinv[node];

    float f0 = 0.f, f1 = 0.f, f2 = 0.f, f3 = 0.f,
          f4 = 0.f, f5 = 0.f, f6 = 0.f, f7 = 0.f;
    if (g == 0) {
        uint4 v = xs4[(long)node * 16 + q];
        acc8(v, f0, f1, f2, f3, f4, f5, f6, f7);
    }
    const int beg = rowstart[node];
    const int end = rowstart[node + 1];
    for (int base = beg; base < end; base += 64) {
        const int m = (end - base < 64) ? (end - base) : 64;
        int sidx = (base + lane < end) ? srclist[base + lane] : 0;
        int k = 0;
        for (; k + 8 <= m; k += 8) {
            int sa = __shfl(sidx, k + g);
            int sb = __shfl(sidx, k + 4 + g);
            uint4 va = xs4[(long)sa * 16 + q];
            uint4 vb = xs4[(long)sb * 16 + q];
            acc8(va, f0, f1, f2, f3, f4, f5, f6, f7);
            acc8(vb, f0, f1, f2, f3, f4, f5, f6, f7);
        }
        for (; k + 4 <= m; k += 4) {
            int sa = __shfl(sidx, k + g);
            uint4 va = xs4[(long)sa * 16 + q];
            acc8(va, f0, f1, f2, f3, f4, f5, f6, f7);
        }
        const int rem = m - k;
        if (rem) {
            int sa = __shfl(sidx, k + g);
            if (g < rem) {
                uint4 va = xs4[(long)sa * 16 + q];
                acc8(va, f0, f1, f2, f3, f4, f5, f6, f7);
            }
        }
    }
#pragma unroll
    for (int off = 16; off < 64; off <<= 1) {
        f0 += __shfl_xor(f0, off); f1 += __shfl_xor(f1, off);
        f2 += __shfl_xor(f2, off); f3 += __shfl_xor(f3, off);
        f4 += __shfl_xor(f4, off); f5 += __shfl_xor(f5, off);
        f6 += __shfl_xor(f6, off); f7 += __shfl_xor(f7, off);
    }
    if (g == 0) {
        uint4 o;
        o.x = pack_bf16(f0 * di, f1 * di);
        o.y = pack_bf16(f2 * di, f3 * di);
        o.z = pack_bf16(f4 * di, f5 * di);
        o.w = pack_bf16(f6 * di, f7 * di);
        agg4[(long)node * 16 + q] = o;
    }
}

// fallback standalone MFMA transform (tier-2)
__global__ __launch_bounds__(256) void k_mfma_transform(
        const unsigned short* __restrict__ A, const unsigned short* __restrict__ WT,
        const float* __restrict__ bias, const float* __restrict__ du,
        float* __restrict__ out, int n, int ntiles) {
    const int wave  = threadIdx.x >> 6;
    const int lane  = threadIdx.x & 63;
    const int rhalf = wave >> 1;
    const int cg    = wave & 1;
    const int lr    = lane & 15;
    const int g     = lane >> 4;
    const int lk8   = g * 8;

    const int t = blockIdx.x;
    if (t >= ntiles) return;
    const long row0 = (long)t * 32 + rhalf * 16;
    const long grow = row0 + lr;

    long ar = grow; if (ar >= n) ar = n - 1;
    short8 afr[4];
#pragma unroll
    for (int ks = 0; ks < 4; ++ks)
        afr[ks] = *reinterpret_cast<const short8*>(A + ar * DIM + ks * 32 + lk8);

    const float inv_keep = 1.0f / 0.9f;
#pragma unroll
    for (int ct = 0; ct < 4; ++ct) {
        const int colbase = cg * 64 + ct * 16;
        f32x4 acc = {0.f, 0.f, 0.f, 0.f};
#pragma unroll
        for (int ks = 0; ks < 4; ++ks) {
            short8 wfr = *reinterpret_cast<const short8*>(
                WT + (long)(colbase + lr) * DIM + ks * 32 + lk8);
            acc = __builtin_amdgcn_mfma_f32_16x16x32_bf16(wfr, afr[ks], acc, 0, 0, 0);
        }
        if (grow < n) {
            const int gcol = colbase + g * 4;
            float4 bb = *reinterpret_cast<const float4*>(bias + gcol);
            float4 u  = *reinterpret_cast<const float4*>(du + grow * DIM + gcol);
            float4 v;
            v.x = acc[0] + bb.x; v.y = acc[1] + bb.y;
            v.z = acc[2] + bb.z; v.w = acc[3] + bb.w;
            v.x = (u.x >= 0.1f) ? fmaxf(v.x, 0.f) * inv_keep : 0.f;
            v.y = (u.y >= 0.1f) ? fmaxf(v.y, 0.f) * inv_keep : 0.f;
            v.z = (u.z >= 0.1f) ? fmaxf(v.z, 0.f) * inv_keep : 0.f;
            v.w = (u.w >= 0.1f) ? fmaxf(v.w, 0.f) * inv_keep : 0.f;
            *reinterpret_cast<float4*>(out + grow * DIM + gcol) = v;
        }
    }
}

extern "C" void kernel_launch(void* const* d_in, const int* in_sizes, int n_in,
                              void* d_out, int out_size, void* d_ws, size_t ws_size,
                              hipStream_t stream) {
    const float* x  = (const float*)d_in[0];
    const int*   ei = (const int*)d_in[1];    // [2,E] int32: row0=src, row1=dst
    const float* W  = (const float*)d_in[2];
    const float* b  = (const float*)d_in[3];
    const float* du = (const float*)d_in[4];
    float* out = (float*)d_out;

    const int n = in_sizes[0] / DIM;
    const int E = in_sizes[1] / 2;

    auto al = [](size_t v) { return (v + 255) & ~(size_t)255; };
    char* ws = (char*)d_ws;

    const int NBUCK = (n + 511) >> 9;
    const int NB1   = (E + EPB1 - 1) / EPB1;

    // ---- tier-3 layout ----
    size_t o_dinv = 0;
    size_t o_rs   = o_dinv + al((size_t)n * 4);
    size_t o_src  = o_rs   + al(((size_t)n + 1) * 4);
    size_t o_xs   = o_src  + al((size_t)E * 4);
    size_t o_agg  = o_xs   + al((size_t)n * DIM * 2);
    size_t o_wt   = o_agg  + al((size_t)n * DIM * 2);
    size_t o_H    = o_wt   + al((size_t)DIM * DIM * 2);
    size_t o_tot  = o_H    + al((size_t)NBUCK * NB1 * 4);
    size_t o_bb   = o_tot  + al((size_t)NBUCK * 4);
    size_t o_ebuf = o_bb   + al(((size_t)NBUCK + 1) * 4);
    size_t need3  = o_ebuf + (size_t)E * 4;

    float* dinv     = (float*)(ws + o_dinv);
    int*   rowstart = (int*)(ws + o_rs);
    int*   srclist  = (int*)(ws + o_src);
    unsigned* xs    = (unsigned*)(ws + o_xs);
    unsigned* agg   = (unsigned*)(ws + o_agg);
    unsigned short* wt = (unsigned short*)(ws + o_wt);
    int*   H        = (int*)(ws + o_H);
    int*   tot      = (int*)(ws + o_tot);
    int*   binbase  = (int*)(ws + o_bb);
    unsigned* ebuf  = (unsigned*)(ws + o_ebuf);

    const int bs = 256;

    if (ws_size >= need3 && NBUCK <= 512 && NB1 <= 512) {
        (void)hipMemsetAsync(tot, 0, (size_t)NBUCK * 4, stream);
        k_hist1<<<NB1 + 8, 512, 0, stream>>>(ei + E, E, H, tot, NB1, NBUCK, W, wt);
        k_scanB<<<NBUCK, 512, 0, stream>>>(H, tot, binbase, NB1, NBUCK, E);
        k_scatter1<<<NB1, 512, 0, stream>>>(ei, E, H, ebuf, NB1, NBUCK);
        k_bucket2<<<NBUCK, 512, 0, stream>>>(ebuf, binbase, srclist, rowstart, dinv,
                                             x, xs, n, E);

        int ntiles16 = (n + 15) / 16;
        k_gather_mfma<<<ntiles16, 512, 0, stream>>>(rowstart, srclist,
                                                    (const uint4*)xs, dinv,
                                                    wt, b, du, out, n);
        return;
    }

    // ---- fallback tiers: atomic CSR build ----
    size_t f_dinv = 0;
    size_t f_hist = f_dinv + al((size_t)n * 4);
    size_t f_rs   = f_hist + al((size_t)n * 4);
    size_t f_bsum = f_rs   + al(((size_t)n + 1) * 4);
    size_t f_src  = f_bsum + 1024;
    size_t f_xs   = f_src  + al((size_t)E * 4);
    size_t f_agg  = f_xs   + al((size_t)n * DIM * 2);
    size_t f_wt   = f_agg  + al((size_t)n * DIM * 2);
    size_t need1  = f_agg;
    size_t need2  = f_wt + (size_t)DIM * DIM * 2;

    float* fdinv     = (float*)(ws + f_dinv);
    int*   fhist     = (int*)(ws + f_hist);
    int*   frowstart = (int*)(ws + f_rs);
    int*   fbsum     = (int*)(ws + f_bsum);
    int*   fsrclist  = (int*)(ws + f_src);
    unsigned* fxs    = (unsigned*)(ws + f_xs);
    unsigned* fagg   = (unsigned*)(ws + f_agg);
    unsigned short* fwt = (unsigned short*)(ws + f_wt);

    const int B = (n + 1023) / 1024;
    (void)hipMemsetAsync(fhist, 0, (size_t)n * 4, stream);
    k_hist<<<(E + bs - 1) / bs, bs, 0, stream>>>(ei + E, E, fhist);
    k_dinv<<<(n + bs - 1) / bs, bs, 0, stream>>>(fhist, fdinv, n);
    k_scan1<<<B, 256, 0, stream>>>(fhist, frowstart, fbsum, n);
    k_scan2<<<1, 256, 0, stream>>>(fbsum, B);
    k_scan3<<<(n + 1 + bs - 1) / bs, bs, 0, stream>>>(frowstart, fbsum, n, E);
    (void)hipMemsetAsync(fhist, 0, (size_t)n * 4, stream);
    k_fill<<<(E + bs - 1) / bs, bs, 0, stream>>>(ei, E, frowstart, fhist, fsrclist);

    if (ws_size >= need2) {
        long t_x = (long)n * D4;
        k_xprep<<<(int)((t_x + bs - 1) / bs), bs, 0, stream>>>(x, fdinv, fxs, n);
        k_wprep<<<(DIM * DIM + bs - 1) / bs, bs, 0, stream>>>(W, fwt);
        k_gather_bb<<<(n + 3) / 4, 256, 0, stream>>>(frowstart, fsrclist,
                                                     (const uint4*)fxs, fdinv,
                                                     (uint4*)fagg, n);
        int ntiles = (n + 31) / 32;
        k_mfma_transform<<<ntiles, 256, 0, stream>>>((const unsigned short*)fagg, fwt,
                                                     b, du, out, n, ntiles);
    } else if (ws_size >= need1) {
        long t_x = (long)n * D4;
        k_xprep<<<(int)((t_x + bs - 1) / bs), bs, 0, stream>>>(x, fdinv, fxs, n);
        k_gather_bf<<<(n + 3) / 4, 256, 0, stream>>>(frowstart, fsrclist, fxs, fdinv, out, n);
    }
}